// Round 2
// baseline (309.412 us; speedup 1.0000x reference)
//
#include <hip/hip_runtime.h>

// Problem constants
#define BATCH 512
#define HWIMG 78400      // 280*280
#define WROW  280
#define KSZ   28
#define PNUM  100        // 10x10 patches
#define FNUM  16
#define ONUM  10

__global__ __launch_bounds__(256) void init_out(const float* __restrict__ dec_b,
                                                float* __restrict__ out) {
    int i = blockIdx.x * 256 + threadIdx.x;
    if (i < BATCH * ONUM) out[i] = dec_b[i % ONUM];
}

// Block: one patch p, 16 batches, 16 filters. 256 threads = kg(8) x fg(4) x bg(8).
// Per-thread register tile: 2 batches x 4 filters, k-sliced by kg (float4 each).
// Grid = 100 * 32 = 3200 blocks * 4 waves = 12800 waves -> full occupancy headroom.
__global__ __launch_bounds__(256, 6) void lcn_fused(
    const float* __restrict__ x,      // (512,1,280,280)
    const float* __restrict__ weight, // (1600,1,28,28)  index (f*100+p)*784
    const float* __restrict__ bias,   // (1600,1)        index  f*100+p
    const float* __restrict__ dec_w,  // (10,1600)       index  o*1600+f*100+p
    float* __restrict__ out)          // (512,10) pre-initialized with dec_b
{
    const int t  = threadIdx.x;
    const int kg = t & 7;           // k-slice group (lane bits 0..2)
    const int fg = (t >> 3) & 3;    // filter group  (lane bits 3..4)
    const int bg = t >> 5;          // batch group   0..7 (bit 5 = wave-internal)
    const int bx = blockIdx.x;
    const int p  = bx >> 5;         // 0..99
    const int bt = bx & 31;         // batch tile 0..31
    const int pr = p / 10, pc = p % 10;
    const int b0 = bt * 16 + bg * 2;

    // kg==7 would read k=28..31 (past the patch row): clamp to 24, zero later.
    const int kq = (kg < 7) ? kg * 4 : 24;

    const float* xp0 = x + (size_t)(b0    ) * HWIMG + (size_t)pr * 28 * WROW + pc * 28 + kq;
    const float* xp1 = x + (size_t)(b0 + 1) * HWIMG + (size_t)pr * 28 * WROW + pc * 28 + kq;
    const float* wp  = weight + (size_t)((fg * 4) * PNUM + p) * 784 + kq;   // filters stride 100*784

    float acc[2][4];
#pragma unroll
    for (int i = 0; i < 2; ++i)
#pragma unroll
        for (int j = 0; j < 4; ++j) acc[i][j] = 0.f;

    // Software-pipelined over kernel rows: x loads double-buffered.
    float4 a0[2], a1[2];
    a0[0] = *reinterpret_cast<const float4*>(xp0);
    a0[1] = *reinterpret_cast<const float4*>(xp1);

#pragma unroll 3
    for (int kr = 0; kr < KSZ; ++kr) {
        if (kr + 1 < KSZ) {
            a1[0] = *reinterpret_cast<const float4*>(xp0 + (kr + 1) * WROW);
            a1[1] = *reinterpret_cast<const float4*>(xp1 + (kr + 1) * WROW);
        }
        float4 wv[4];
#pragma unroll
        for (int j = 0; j < 4; ++j)
            wv[j] = *reinterpret_cast<const float4*>(wp + (size_t)j * (PNUM * 784) + kr * KSZ);
#pragma unroll
        for (int i = 0; i < 2; ++i) {
#pragma unroll
            for (int j = 0; j < 4; ++j) {
                acc[i][j] = fmaf(a0[i].x, wv[j].x, acc[i][j]);
                acc[i][j] = fmaf(a0[i].y, wv[j].y, acc[i][j]);
                acc[i][j] = fmaf(a0[i].z, wv[j].z, acc[i][j]);
                acc[i][j] = fmaf(a0[i].w, wv[j].w, acc[i][j]);
            }
        }
        a0[0] = a1[0];
        a0[1] = a1[1];
    }

    // kg==7 computed on duplicated data: zero it.
    const float km = (kg < 7) ? 1.f : 0.f;
#pragma unroll
    for (int i = 0; i < 2; ++i)
#pragma unroll
        for (int j = 0; j < 4; ++j) acc[i][j] *= km;

    // Reduce over kg (lane bits 0..2) — butterfly; all lanes end with the sum.
#pragma unroll
    for (int d = 1; d < 8; d <<= 1)
#pragma unroll
        for (int i = 0; i < 2; ++i)
#pragma unroll
            for (int j = 0; j < 4; ++j)
                acc[i][j] += __shfl_xor(acc[i][j], d, 64);

    // bias + relu
    float y[2][4];
#pragma unroll
    for (int j = 0; j < 4; ++j) {
        const float bs = bias[(fg * 4 + j) * PNUM + p];
#pragma unroll
        for (int i = 0; i < 2; ++i) {
            float v = acc[i][j] + bs;
            y[i][j] = v > 0.f ? v : 0.f;
        }
    }

    // Decoder: split the 10 outputs across kg lanes 0..4 (2 outputs each).
    float po[2][2];
    const int  o0  = kg * 2;
    const bool act = (kg < 5);
    if (act) {
        float dwv[4][2];
#pragma unroll
        for (int j = 0; j < 4; ++j)
#pragma unroll
            for (int oo = 0; oo < 2; ++oo)
                dwv[j][oo] = dec_w[(size_t)(o0 + oo) * (PNUM * FNUM) + (fg * 4 + j) * PNUM + p];
#pragma unroll
        for (int i = 0; i < 2; ++i)
#pragma unroll
            for (int oo = 0; oo < 2; ++oo) {
                float s = 0.f;
#pragma unroll
                for (int j = 0; j < 4; ++j) s = fmaf(y[i][j], dwv[j][oo], s);
                po[i][oo] = s;
            }
    } else {
#pragma unroll
        for (int i = 0; i < 2; ++i) { po[i][0] = 0.f; po[i][1] = 0.f; }
    }

    // Reduce over fg (lane bits 3..4); kg bits preserved so zero lanes stay isolated.
#pragma unroll
    for (int d = 8; d < 32; d <<= 1)
#pragma unroll
        for (int i = 0; i < 2; ++i)
#pragma unroll
            for (int oo = 0; oo < 2; ++oo)
                po[i][oo] += __shfl_xor(po[i][oo], d, 64);

    if (act && fg == 0) {
#pragma unroll
        for (int i = 0; i < 2; ++i)
#pragma unroll
            for (int oo = 0; oo < 2; ++oo)
                atomicAdd(&out[(size_t)(b0 + i) * ONUM + o0 + oo], po[i][oo]);
    }
}

extern "C" void kernel_launch(void* const* d_in, const int* in_sizes, int n_in,
                              void* d_out, int out_size, void* d_ws, size_t ws_size,
                              hipStream_t stream) {
    const float* x     = (const float*)d_in[0];
    const float* w     = (const float*)d_in[1];
    const float* bias  = (const float*)d_in[2];
    const float* dec_w = (const float*)d_in[3];
    const float* dec_b = (const float*)d_in[4];
    float* out = (float*)d_out;

    init_out<<<(BATCH * ONUM + 255) / 256, 256, 0, stream>>>(dec_b, out);
    lcn_fused<<<(BATCH / 16) * PNUM, 256, 0, stream>>>(x, w, bias, dec_w, out);
}